// Round 1
// baseline (1581.214 us; speedup 1.0000x reference)
//
#include <hip/hip_runtime.h>
#include <hip/hip_bf16.h>
#include <math.h>

typedef __attribute__((ext_vector_type(8))) short bf16x8;
typedef __attribute__((ext_vector_type(4))) float f32x4;
typedef __attribute__((ext_vector_type(8))) unsigned short u16x8;

#define M_ROWS 100000
#define NBLK   1563   // ceil(100000/64)

static __device__ __forceinline__ unsigned short f2bf(float f) {
  union { float f; unsigned u; } cv; cv.f = f;
  unsigned u = cv.u;
  return (unsigned short)((u + 0x7fffu + ((u >> 16) & 1u)) >> 16);  // RNE
}

static __device__ __forceinline__ f32x4 mfma16(bf16x8 a, bf16x8 b, f32x4 c) {
  return __builtin_amdgcn_mfma_f32_16x16x32_bf16(a, b, c, 0, 0, 0);
}

// ---------- prep: transpose + bf16-convert weights; zero agg1 ----------
__global__ void prep_kernel(const float* __restrict__ Wc, const float* __restrict__ W1,
                            const float* __restrict__ W2,
                            unsigned short* __restrict__ Wct, unsigned short* __restrict__ W1t,
                            unsigned short* __restrict__ W2t, float* __restrict__ agg1) {
  int i = blockIdx.x * blockDim.x + threadIdx.x;
  if (i < 1024) agg1[i] = 0.0f;
  if (i < 512 * 1024) {                 // Wct[c][k] = Wc[k][c]
    int c = i >> 10, k = i & 1023;
    Wct[i] = f2bf(Wc[k * 512 + c]);
  } else if (i < 768 * 1024) {          // W1t[c][k] = W1[k][c]
    int j = i - 512 * 1024;
    int c = j >> 10, k = j & 1023;
    W1t[j] = f2bf(W1[k * 256 + c]);
  } else if (i < 1024 * 1024) {         // W2t
    int j = i - 768 * 1024;
    int c = j >> 10, k = j & 1023;
    W2t[j] = f2bf(W2[k * 256 + c]);
  }
}

// ---------- kernel A: U1=x@W1, U2=x@W2 -> a=tanh(u1+b1)*sig(u2+b2) -> A=a@W3+b3 ----------
// BM=64 rows/block, all 256 j-cols, 8 waves: wave grid 2(M)x4(J), wave tile 32 rows x 64 j.
__launch_bounds__(512)
__global__ void kernelA(const float* __restrict__ x,
                        const unsigned short* __restrict__ W1t, const unsigned short* __restrict__ W2t,
                        const float* __restrict__ b1, const float* __restrict__ b2,
                        const float* __restrict__ W3, const float* __restrict__ b3,
                        float* __restrict__ Ag) {
  __shared__ unsigned short xl[64 * 32];    // 4KB  [row][k]
  __shared__ unsigned short w1l[256 * 32];  // 16KB [j][k]
  __shared__ unsigned short w2l[256 * 32];  // 16KB
  __shared__ float Alds[64 * 2];

  const int tid = threadIdx.x;
  const int lane = tid & 63, wid = tid >> 6;
  const int wm = wid >> 2, wj = wid & 3;
  const int lr = lane & 15, lg = lane >> 4;
  const int m0 = blockIdx.x * 64;

  f32x4 acc1[2][4], acc2[2][4];
#pragma unroll
  for (int m = 0; m < 2; m++)
#pragma unroll
    for (int n = 0; n < 4; n++) {
      acc1[m][n] = (f32x4){0.f, 0.f, 0.f, 0.f};
      acc2[m][n] = (f32x4){0.f, 0.f, 0.f, 0.f};
    }

  // x staging: thread -> (row = tid/8, 4 k's at (tid%8)*4); lds flat = tid*4 elems
  const int xr = tid >> 3;
  const bool xvalid = (m0 + xr) < M_ROWS;
  const float* xsrc = x + (size_t)(m0 + xr) * 1024 + ((tid & 7) << 2);
  unsigned short* xdst = &xl[tid * 4];

  // W staging: thread -> tile elems [tid*8, tid*8+8) and +512-thread chunk
  const unsigned short* w1src = W1t + (size_t)(tid >> 2) * 1024 + ((tid & 3) << 3);
  const unsigned short* w2src = W2t + (size_t)(tid >> 2) * 1024 + ((tid & 3) << 3);
  unsigned short* w1dst = &w1l[tid * 8];
  unsigned short* w2dst = &w2l[tid * 8];

  // fragment pointers (constant across K-steps; tiles rewritten in place)
  const bf16x8* ap0 = (const bf16x8*)&xl[(wm * 32 + 0 + lr) * 32 + lg * 8];
  const bf16x8* ap1 = (const bf16x8*)&xl[(wm * 32 + 16 + lr) * 32 + lg * 8];
  const bf16x8* b1p[4]; const bf16x8* b2p[4];
#pragma unroll
  for (int n = 0; n < 4; n++) {
    b1p[n] = (const bf16x8*)&w1l[(wj * 64 + n * 16 + lr) * 32 + lg * 8];
    b2p[n] = (const bf16x8*)&w2l[(wj * 64 + n * 16 + lr) * 32 + lg * 8];
  }

  for (int ks = 0; ks < 32; ks++) {
    const int k0 = ks * 32;
    float4 xv = make_float4(0.f, 0.f, 0.f, 0.f);
    if (xvalid) xv = *(const float4*)(xsrc + k0);
    ushort4 xb;
    xb.x = f2bf(xv.x); xb.y = f2bf(xv.y); xb.z = f2bf(xv.z); xb.w = f2bf(xv.w);
    *(ushort4*)xdst = xb;
    *(u16x8*)w1dst          = *(const u16x8*)(w1src + k0);
    *(u16x8*)(w1dst + 4096) = *(const u16x8*)(w1src + 131072 + k0);
    *(u16x8*)w2dst          = *(const u16x8*)(w2src + k0);
    *(u16x8*)(w2dst + 4096) = *(const u16x8*)(w2src + 131072 + k0);
    __syncthreads();
    bf16x8 a0 = *ap0, a1 = *ap1;
#pragma unroll
    for (int n = 0; n < 4; n++) {
      bf16x8 bb1 = *b1p[n];
      acc1[0][n] = mfma16(a0, bb1, acc1[0][n]);
      acc1[1][n] = mfma16(a1, bb1, acc1[1][n]);
      bf16x8 bb2 = *b2p[n];
      acc2[0][n] = mfma16(a0, bb2, acc2[0][n]);
      acc2[1][n] = mfma16(a1, bb2, acc2[1][n]);
    }
    __syncthreads();
  }

  // epilogue: a = tanh(u1+b1)*sigmoid(u2+b2); pA[m][r][c] = sum_j a*W3[j][c]
  float pA[2][4][2];
#pragma unroll
  for (int m = 0; m < 2; m++)
#pragma unroll
    for (int r = 0; r < 4; r++) { pA[m][r][0] = 0.f; pA[m][r][1] = 0.f; }

#pragma unroll
  for (int n = 0; n < 4; n++) {
    const int j = wj * 64 + n * 16 + lr;
    const float bb1 = b1[j], bb2 = b2[j];
    const float w30 = W3[j * 2], w31 = W3[j * 2 + 1];
#pragma unroll
    for (int m = 0; m < 2; m++)
#pragma unroll
      for (int r = 0; r < 4; r++) {
        float u1 = acc1[m][n][r] + bb1;
        float u2 = acc2[m][n][r] + bb2;
        float av = tanhf(u1) * (1.0f / (1.0f + __expf(-u2)));
        pA[m][r][0] += av * w30;
        pA[m][r][1] += av * w31;
      }
  }
  // reduce over the 16 lr-lanes (butterfly)
#pragma unroll
  for (int off = 1; off < 16; off <<= 1)
#pragma unroll
    for (int m = 0; m < 2; m++)
#pragma unroll
      for (int r = 0; r < 4; r++) {
        pA[m][r][0] += __shfl_xor(pA[m][r][0], off, 64);
        pA[m][r][1] += __shfl_xor(pA[m][r][1], off, 64);
      }

  if (tid < 128) Alds[tid] = 0.0f;
  __syncthreads();
  if (lr == 0) {
#pragma unroll
    for (int m = 0; m < 2; m++)
#pragma unroll
      for (int r = 0; r < 4; r++) {
        int row = wm * 32 + m * 16 + lg * 4 + r;
        atomicAdd(&Alds[row * 2 + 0], pA[m][r][0]);
        atomicAdd(&Alds[row * 2 + 1], pA[m][r][1]);
      }
  }
  __syncthreads();
  if (tid < 128) {
    int row = tid >> 1, c = tid & 1;
    if (m0 + row < M_ROWS) Ag[(size_t)(m0 + row) * 2 + c] = Alds[tid] + b3[c];
  }
}

// ---------- top-k: top-8 and bottom-8 of A[:,bag_label], jax tie semantics ----------
template <bool MIN>
static __device__ __forceinline__ bool better(float v1, int i1, float v2, int i2) {
  if (MIN) return (v1 < v2) || (v1 == v2 && i1 < i2);
  else     return (v1 > v2) || (v1 == v2 && i1 < i2);
}

template <bool MIN>
static __device__ __forceinline__ void merge_lists(float* vL, int* iL, int t, int s) {
  float av[8], ov[8], mv[8];
  int ai[8], oi[8], mi[8];
#pragma unroll
  for (int p = 0; p < 8; p++) {
    av[p] = vL[t * 8 + p];       ai[p] = iL[t * 8 + p];
    ov[p] = vL[(t + s) * 8 + p]; oi[p] = iL[(t + s) * 8 + p];
  }
#pragma unroll
  for (int p = 0; p < 8; p++) {   // top-8 of union = elementwise best(a[p], o[7-p])
    bool b = better<MIN>(av[p], ai[p], ov[7 - p], oi[7 - p]);
    mv[p] = b ? av[p] : ov[7 - p];
    mi[p] = b ? ai[p] : oi[7 - p];
  }
#define CE(i, j)                                                             \
  { if (!better<MIN>(mv[i], mi[i], mv[j], mi[j])) {                          \
      float tv = mv[i]; mv[i] = mv[j]; mv[j] = tv;                           \
      int tii = mi[i]; mi[i] = mi[j]; mi[j] = tii; } }
  CE(0, 4) CE(1, 5) CE(2, 6) CE(3, 7)
  CE(0, 2) CE(1, 3) CE(4, 6) CE(5, 7)
  CE(0, 1) CE(2, 3) CE(4, 5) CE(6, 7)
#undef CE
#pragma unroll
  for (int p = 0; p < 8; p++) { vL[t * 8 + p] = mv[p]; iL[t * 8 + p] = mi[p]; }
}

__launch_bounds__(256)
__global__ void topk_kernel(const float* __restrict__ Ag, const int* __restrict__ bag_label,
                            int* __restrict__ idxout, float* __restrict__ out) {
  __shared__ float tvL[256 * 8]; __shared__ int tiL[256 * 8];
  __shared__ float bvL[256 * 8]; __shared__ int biL[256 * 8];
  const int t = threadIdx.x;
  const int lab = bag_label[0];
  float tv[8], bv[8]; int ti[8], bi[8];
#pragma unroll
  for (int p = 0; p < 8; p++) {
    tv[p] = -3.4e38f; ti[p] = 0x7fffffff;
    bv[p] =  3.4e38f; bi[p] = 0x7fffffff;
  }
  for (int r = t; r < M_ROWS; r += 256) {
    float v = Ag[(size_t)r * 2 + lab];
    if (v > tv[7] || (v == tv[7] && r < ti[7])) {
      float cv = v; int ci = r;
#pragma unroll
      for (int p = 0; p < 8; p++) {
        bool b = (cv > tv[p]) || (cv == tv[p] && ci < ti[p]);
        if (b) { float t0 = tv[p]; int t1 = ti[p]; tv[p] = cv; ti[p] = ci; cv = t0; ci = t1; }
      }
    }
    if (v < bv[7] || (v == bv[7] && r < bi[7])) {
      float cv = v; int ci = r;
#pragma unroll
      for (int p = 0; p < 8; p++) {
        bool b = (cv < bv[p]) || (cv == bv[p] && ci < bi[p]);
        if (b) { float t0 = bv[p]; int t1 = bi[p]; bv[p] = cv; bi[p] = ci; cv = t0; ci = t1; }
      }
    }
  }
#pragma unroll
  for (int p = 0; p < 8; p++) {
    tvL[t * 8 + p] = tv[p]; tiL[t * 8 + p] = ti[p];
    bvL[t * 8 + p] = bv[p]; biL[t * 8 + p] = bi[p];
  }
  __syncthreads();
  for (int s = 128; s > 0; s >>= 1) {
    if (t < s) {
      merge_lists<false>(tvL, tiL, t, s);
      merge_lists<true>(bvL, biL, t, s);
    }
    __syncthreads();
  }
  if (t == 0) {
#pragma unroll
    for (int p = 0; p < 8; p++) {
      idxout[p] = tiL[p];
      idxout[8 + p] = biL[p];
      out[37 + p] = 1.0f;   // ins_labels: ones then zeros
      out[45 + p] = 0.0f;
    }
  }
}

// ---------- kernel H: h=relu(x@Wc+bc); agg partial += A[r]^T h[r]; scatter selected rows ----------
__launch_bounds__(512)
__global__ void kernelH(const float* __restrict__ x,
                        const unsigned short* __restrict__ Wct,
                        const float* __restrict__ bc,
                        const float* __restrict__ Ag,
                        const int* __restrict__ idx,
                        float* __restrict__ aggP,
                        float* __restrict__ hsel) {
  __shared__ unsigned short xl[64 * 32];    // 4KB
  __shared__ unsigned short wl[512 * 32];   // 32KB [col][k]
  __shared__ float aggL[1024];
  __shared__ int selr[16];

  const int tid = threadIdx.x;
  const int lane = tid & 63, wid = tid >> 6;
  const int wm = wid >> 2, wc = wid & 3;
  const int lr = lane & 15, lg = lane >> 4;
  const int m0 = blockIdx.x * 64;

  f32x4 acc[2][8];
#pragma unroll
  for (int m = 0; m < 2; m++)
#pragma unroll
    for (int n = 0; n < 8; n++) acc[m][n] = (f32x4){0.f, 0.f, 0.f, 0.f};

  const int xr = tid >> 3;
  const bool xvalid = (m0 + xr) < M_ROWS;
  const float* xsrc = x + (size_t)(m0 + xr) * 1024 + ((tid & 7) << 2);
  unsigned short* xdst = &xl[tid * 4];

  const unsigned short* wsrc = Wct + (size_t)(tid >> 2) * 1024 + ((tid & 3) << 3);
  unsigned short* wdst = &wl[tid * 8];

  const bf16x8* ap0 = (const bf16x8*)&xl[(wm * 32 + 0 + lr) * 32 + lg * 8];
  const bf16x8* ap1 = (const bf16x8*)&xl[(wm * 32 + 16 + lr) * 32 + lg * 8];
  const bf16x8* bp[8];
#pragma unroll
  for (int n = 0; n < 8; n++)
    bp[n] = (const bf16x8*)&wl[(wc * 128 + n * 16 + lr) * 32 + lg * 8];

  for (int ks = 0; ks < 32; ks++) {
    const int k0 = ks * 32;
    float4 xv = make_float4(0.f, 0.f, 0.f, 0.f);
    if (xvalid) xv = *(const float4*)(xsrc + k0);
    ushort4 xb;
    xb.x = f2bf(xv.x); xb.y = f2bf(xv.y); xb.z = f2bf(xv.z); xb.w = f2bf(xv.w);
    *(ushort4*)xdst = xb;
    *(u16x8*)wdst           = *(const u16x8*)(wsrc + k0);
    *(u16x8*)(wdst + 4096)  = *(const u16x8*)(wsrc + 131072 + k0);
    *(u16x8*)(wdst + 8192)  = *(const u16x8*)(wsrc + 262144 + k0);
    *(u16x8*)(wdst + 12288) = *(const u16x8*)(wsrc + 393216 + k0);
    __syncthreads();
    bf16x8 a0 = *ap0, a1 = *ap1;
#pragma unroll
    for (int n = 0; n < 8; n++) {
      bf16x8 bb = *bp[n];
      acc[0][n] = mfma16(a0, bb, acc[0][n]);
      acc[1][n] = mfma16(a1, bb, acc[1][n]);
    }
    __syncthreads();
  }

  // epilogue
  if (tid < 16) {
    int r = idx[tid];
    selr[tid] = (r >= m0 && r < m0 + 64) ? (r - m0) : -1;
  }
  aggL[tid] = 0.0f;
  aggL[tid + 512] = 0.0f;
  __syncthreads();

  float av[2][4][2];
#pragma unroll
  for (int m = 0; m < 2; m++)
#pragma unroll
    for (int r = 0; r < 4; r++) {
      int row = m0 + wm * 32 + m * 16 + lg * 4 + r;
      bool valid = row < M_ROWS;
      av[m][r][0] = valid ? Ag[(size_t)row * 2 + 0] : 0.f;
      av[m][r][1] = valid ? Ag[(size_t)row * 2 + 1] : 0.f;
    }

  float contrib[8][2];
#pragma unroll
  for (int n = 0; n < 8; n++) { contrib[n][0] = 0.f; contrib[n][1] = 0.f; }

#pragma unroll
  for (int n = 0; n < 8; n++) {
    const float bcv = bc[wc * 128 + n * 16 + lr];
#pragma unroll
    for (int m = 0; m < 2; m++)
#pragma unroll
      for (int r = 0; r < 4; r++) {
        float h = fmaxf(acc[m][n][r] + bcv, 0.0f);
        acc[m][n][r] = h;  // keep for hsel scatter
        contrib[n][0] += av[m][r][0] * h;
        contrib[n][1] += av[m][r][1] * h;
      }
  }
#pragma unroll
  for (int n = 0; n < 8; n++)
#pragma unroll
    for (int c = 0; c < 2; c++) {
      contrib[n][c] += __shfl_xor(contrib[n][c], 16, 64);
      contrib[n][c] += __shfl_xor(contrib[n][c], 32, 64);
    }
  if (lg == 0) {
#pragma unroll
    for (int n = 0; n < 8; n++) {
      atomicAdd(&aggL[wc * 128 + n * 16 + lr], contrib[n][0]);
      atomicAdd(&aggL[512 + wc * 128 + n * 16 + lr], contrib[n][1]);
    }
  }
  // scatter selected h rows
#pragma unroll
  for (int s = 0; s < 16; s++) {
    int rl = selr[s];
    if (rl < 0 || (rl >> 5) != wm) continue;
#pragma unroll
    for (int m = 0; m < 2; m++)
#pragma unroll
      for (int r = 0; r < 4; r++)
        if (rl == wm * 32 + m * 16 + lg * 4 + r) {
#pragma unroll
          for (int n = 0; n < 8; n++)
            hsel[s * 512 + wc * 128 + n * 16 + lr] = acc[m][n][r];
        }
  }
  __syncthreads();
  aggP[(size_t)blockIdx.x * 1024 + tid] = aggL[tid];
  aggP[(size_t)blockIdx.x * 1024 + 512 + tid] = aggL[tid + 512];
}

// ---------- reduce agg partials ----------
__launch_bounds__(256)
__global__ void reduce_kernel(const float* __restrict__ aggP, float* __restrict__ agg1) {
  int tcol = (blockIdx.x & 3) * 256 + threadIdx.x;
  int g = blockIdx.x >> 2;
  int b0 = g * 98, b1 = min(NBLK, b0 + 98);
  float s = 0.f;
  for (int b = b0; b < b1; b++) s += aggP[(size_t)b * 1024 + tcol];
  atomicAdd(&agg1[tcol], s);
}

// ---------- slide score / softmax / argmax ----------
__launch_bounds__(1024)
__global__ void score_kernel(const float* __restrict__ agg1, const float* __restrict__ Wbag,
                             const float* __restrict__ bbag, float* __restrict__ out) {
  __shared__ float red[1024];
  int t = threadIdx.x;
  red[t] = agg1[t] * Wbag[t & 511];
  __syncthreads();
  for (int off = 256; off > 0; off >>= 1) {
    if ((t & 511) < off) red[t] += red[t + off];
    __syncthreads();
  }
  if (t == 0) {
    float s0 = red[0] + bbag[0];
    float s1 = red[512] + bbag[0];
    out[0] = s0; out[1] = s1;
    out[2] = (s1 > s0) ? 1.0f : 0.0f;      // argmax, first-max-wins tie
    float mx = fmaxf(s0, s1);
    float e0 = __expf(s0 - mx), e1 = __expf(s1 - mx);
    out[3] = e0 / (e0 + e1);
    out[4] = e1 / (e0 + e1);
  }
}

// ---------- instance head: softmax(hsel @ Wins + bins) ----------
__launch_bounds__(512)
__global__ void ins_kernel(const float* __restrict__ hsel, const float* __restrict__ Wins,
                           const float* __restrict__ bins, float* __restrict__ out) {
  int lane = threadIdx.x & 63;
  int w = threadIdx.x >> 6;  // 8 waves, 2 rows each
#pragma unroll
  for (int si = 0; si < 2; si++) {
    int s = w * 2 + si;
    float z0 = 0.f, z1 = 0.f;
#pragma unroll
    for (int q = 0; q < 8; q++) {
      int c = lane * 8 + q;
      float h = hsel[s * 512 + c];
      z0 += h * Wins[c * 2 + 0];
      z1 += h * Wins[c * 2 + 1];
    }
#pragma unroll
    for (int off = 1; off < 64; off <<= 1) {
      z0 += __shfl_xor(z0, off, 64);
      z1 += __shfl_xor(z1, off, 64);
    }
    if (lane == 0) {
      z0 += bins[0]; z1 += bins[1];
      float mx = fmaxf(z0, z1);
      float e0 = __expf(z0 - mx), e1 = __expf(z1 - mx);
      float d = e0 + e1;
      out[5 + s * 2 + 0] = e0 / d;
      out[5 + s * 2 + 1] = e1 / d;
    }
  }
}

extern "C" void kernel_launch(void* const* d_in, const int* in_sizes, int n_in,
                              void* d_out, int out_size, void* d_ws, size_t ws_size,
                              hipStream_t stream) {
  (void)in_sizes; (void)n_in; (void)out_size; (void)ws_size;
  const float* x    = (const float*)d_in[0];
  const float* Wc   = (const float*)d_in[1];
  const float* bc   = (const float*)d_in[2];
  const float* W1   = (const float*)d_in[3];
  const float* b1   = (const float*)d_in[4];
  const float* W2   = (const float*)d_in[5];
  const float* b2   = (const float*)d_in[6];
  const float* W3   = (const float*)d_in[7];
  const float* b3   = (const float*)d_in[8];
  const float* Wbag = (const float*)d_in[9];
  const float* bbag = (const float*)d_in[10];
  const float* Wins = (const float*)d_in[11];
  const float* bins = (const float*)d_in[12];
  const int* bag_label = (const int*)d_in[13];
  float* out = (float*)d_out;
  char* ws = (char*)d_ws;

  // ws layout (bytes)
  unsigned short* Wct = (unsigned short*)(ws);                    // 1048576
  unsigned short* W1t = (unsigned short*)(ws + 1048576);          // 524288
  unsigned short* W2t = (unsigned short*)(ws + 1572864);          // 524288
  float* Ag   = (float*)(ws + 2097152);                           // 100000*2*4 = 800000
  float* aggP = (float*)(ws + 2897152);                           // 1563*1024*4 = 6402048
  int*   idx  = (int*)  (ws + 9299200);                           // 64
  float* hsel = (float*)(ws + 9299264);                           // 16*512*4 = 32768
  float* agg1 = (float*)(ws + 9332032);                           // 4096

  prep_kernel<<<4096, 256, 0, stream>>>(Wc, W1, W2, Wct, W1t, W2t, agg1);
  kernelA<<<NBLK, 512, 0, stream>>>(x, W1t, W2t, b1, b2, W3, b3, Ag);
  topk_kernel<<<1, 256, 0, stream>>>(Ag, bag_label, idx, out);
  kernelH<<<NBLK, 512, 0, stream>>>(x, Wct, bc, Ag, idx, aggP, hsel);
  reduce_kernel<<<64, 256, 0, stream>>>(aggP, agg1);
  score_kernel<<<1, 1024, 0, stream>>>(agg1, Wbag, bbag, out);
  ins_kernel<<<1, 512, 0, stream>>>(hsel, Wins, bins, out);
}

// Round 2
// 1049.002 us; speedup vs baseline: 1.5074x; 1.5074x over previous
//
#include <hip/hip_runtime.h>
#include <hip/hip_bf16.h>
#include <math.h>

typedef __attribute__((ext_vector_type(8))) short bf16x8;
typedef __attribute__((ext_vector_type(4))) float f32x4;

#define M_ROWS 100000
#define NBLK   1563   // ceil(100000/64)

static __device__ __forceinline__ unsigned short f2bf(float f) {
  union { float f; unsigned u; } cv; cv.f = f;
  unsigned u = cv.u;
  return (unsigned short)((u + 0x7fffu + ((u >> 16) & 1u)) >> 16);  // RNE
}

static __device__ __forceinline__ f32x4 mfma16(bf16x8 a, bf16x8 b, f32x4 c) {
  return __builtin_amdgcn_mfma_f32_16x16x32_bf16(a, b, c, 0, 0, 0);
}

// async global(per-lane) -> LDS(wave-uniform base + lane*16) DMA, 16B/lane
static __device__ __forceinline__ void gload_lds16(const unsigned short* g, unsigned short* l) {
  __builtin_amdgcn_global_load_lds((const __attribute__((address_space(1))) unsigned int*)g,
                                   (__attribute__((address_space(3))) unsigned int*)l, 16, 0, 0);
}

// ---------- prep: transpose + bf16-convert weights; zero agg1 ----------
__global__ void prep_kernel(const float* __restrict__ Wc, const float* __restrict__ W1,
                            const float* __restrict__ W2,
                            unsigned short* __restrict__ Wct, unsigned short* __restrict__ W1t,
                            unsigned short* __restrict__ W2t, float* __restrict__ agg1) {
  int i = blockIdx.x * blockDim.x + threadIdx.x;
  if (i < 1024) agg1[i] = 0.0f;
  if (i < 512 * 1024) {                 // Wct[c][k] = Wc[k][c]
    int c = i >> 10, k = i & 1023;
    Wct[i] = f2bf(Wc[k * 512 + c]);
  } else if (i < 768 * 1024) {          // W1t[c][k] = W1[k][c]
    int j = i - 512 * 1024;
    int c = j >> 10, k = j & 1023;
    W1t[j] = f2bf(W1[k * 256 + c]);
  } else if (i < 1024 * 1024) {         // W2t
    int j = i - 768 * 1024;
    int c = j >> 10, k = j & 1023;
    W2t[j] = f2bf(W2[k * 256 + c]);
  }
}

// ---------- kernel A: U1=x@W1, U2=x@W2 -> a=tanh(u1+b1)*sig(u2+b2) -> A=a@W3+b3 ----------
// BM=64 rows/block, all 256 j-cols, 8 waves: wave grid 2(M)x4(J), wave tile 32 rows x 64 j.
__launch_bounds__(512)
__global__ void kernelA(const float* __restrict__ x,
                        const unsigned short* __restrict__ W1t, const unsigned short* __restrict__ W2t,
                        const float* __restrict__ b1, const float* __restrict__ b2,
                        const float* __restrict__ W3, const float* __restrict__ b3,
                        float* __restrict__ Ag) {
  __shared__ unsigned short xl[64 * 32];    // 4KB  [row][k]
  __shared__ unsigned short w1l[256 * 32];  // 16KB [j][k]
  __shared__ unsigned short w2l[256 * 32];  // 16KB
  __shared__ float Alds[64 * 2];

  const int tid = threadIdx.x;
  const int lane = tid & 63, wid = tid >> 6;
  const int wm = wid >> 2, wj = wid & 3;
  const int lr = lane & 15, lg = lane >> 4;
  const int m0 = blockIdx.x * 64;

  f32x4 acc1[2][4], acc2[2][4];
#pragma unroll
  for (int m = 0; m < 2; m++)
#pragma unroll
    for (int n = 0; n < 4; n++) {
      acc1[m][n] = (f32x4){0.f, 0.f, 0.f, 0.f};
      acc2[m][n] = (f32x4){0.f, 0.f, 0.f, 0.f};
    }

  // x staging: thread -> (row = tid/8, 4 k's at (tid%8)*4); lds flat = tid*4 elems
  const int xr = tid >> 3;
  const bool xvalid = (m0 + xr) < M_ROWS;
  const float* xsrc = x + (size_t)(m0 + xr) * 1024 + ((tid & 7) << 2);
  unsigned short* xdst = &xl[tid * 4];

  // W staging via global_load_lds: wave w covers LDS shorts [q*4096 + w*512, +512)
  // lane l writes 8 shorts; src col = q*128 + w*16 + (l>>2), kk = (l&3)*8
  const unsigned short* w1base = W1t + (size_t)(wid * 16 + (lane >> 2)) * 1024 + ((lane & 3) << 3);
  const unsigned short* w2base = W2t + (size_t)(wid * 16 + (lane >> 2)) * 1024 + ((lane & 3) << 3);
  unsigned short* w1dst0 = &w1l[wid * 512];
  unsigned short* w1dst1 = &w1l[4096 + wid * 512];
  unsigned short* w2dst0 = &w2l[wid * 512];
  unsigned short* w2dst1 = &w2l[4096 + wid * 512];

  // fragment pointers (constant across K-steps; tiles rewritten in place)
  const bf16x8* ap0 = (const bf16x8*)&xl[(wm * 32 + 0 + lr) * 32 + lg * 8];
  const bf16x8* ap1 = (const bf16x8*)&xl[(wm * 32 + 16 + lr) * 32 + lg * 8];
  const bf16x8* b1p[4]; const bf16x8* b2p[4];
#pragma unroll
  for (int n = 0; n < 4; n++) {
    b1p[n] = (const bf16x8*)&w1l[(wj * 64 + n * 16 + lr) * 32 + lg * 8];
    b2p[n] = (const bf16x8*)&w2l[(wj * 64 + n * 16 + lr) * 32 + lg * 8];
  }

  for (int ks = 0; ks < 32; ks++) {
    const int k0 = ks * 32;
    gload_lds16(w1base + k0, w1dst0);
    gload_lds16(w1base + 131072 + k0, w1dst1);
    gload_lds16(w2base + k0, w2dst0);
    gload_lds16(w2base + 131072 + k0, w2dst1);
    float4 xv = make_float4(0.f, 0.f, 0.f, 0.f);
    if (xvalid) xv = *(const float4*)(xsrc + k0);
    ushort4 xb;
    xb.x = f2bf(xv.x); xb.y = f2bf(xv.y); xb.z = f2bf(xv.z); xb.w = f2bf(xv.w);
    *(ushort4*)xdst = xb;
    __syncthreads();   // drains vmcnt (gload_lds) + lgkm (ds_write) before use
    bf16x8 a0 = *ap0, a1 = *ap1;
#pragma unroll
    for (int n = 0; n < 4; n++) {
      bf16x8 bb1 = *b1p[n];
      acc1[0][n] = mfma16(a0, bb1, acc1[0][n]);
      acc1[1][n] = mfma16(a1, bb1, acc1[1][n]);
      bf16x8 bb2 = *b2p[n];
      acc2[0][n] = mfma16(a0, bb2, acc2[0][n]);
      acc2[1][n] = mfma16(a1, bb2, acc2[1][n]);
    }
    __syncthreads();
  }

  // epilogue: a = tanh(u1+b1)*sigmoid(u2+b2); pA[m][r][c] = sum_j a*W3[j][c]
  float pA[2][4][2];
#pragma unroll
  for (int m = 0; m < 2; m++)
#pragma unroll
    for (int r = 0; r < 4; r++) { pA[m][r][0] = 0.f; pA[m][r][1] = 0.f; }

#pragma unroll
  for (int n = 0; n < 4; n++) {
    const int j = wj * 64 + n * 16 + lr;
    const float bb1 = b1[j], bb2 = b2[j];
    const float w30 = W3[j * 2], w31 = W3[j * 2 + 1];
#pragma unroll
    for (int m = 0; m < 2; m++)
#pragma unroll
      for (int r = 0; r < 4; r++) {
        float u1 = acc1[m][n][r] + bb1;
        float u2 = acc2[m][n][r] + bb2;
        float av = tanhf(u1) * (1.0f / (1.0f + __expf(-u2)));
        pA[m][r][0] += av * w30;
        pA[m][r][1] += av * w31;
      }
  }
  // reduce over the 16 lr-lanes (butterfly)
#pragma unroll
  for (int off = 1; off < 16; off <<= 1)
#pragma unroll
    for (int m = 0; m < 2; m++)
#pragma unroll
      for (int r = 0; r < 4; r++) {
        pA[m][r][0] += __shfl_xor(pA[m][r][0], off, 64);
        pA[m][r][1] += __shfl_xor(pA[m][r][1], off, 64);
      }

  if (tid < 128) Alds[tid] = 0.0f;
  __syncthreads();
  if (lr == 0) {
#pragma unroll
    for (int m = 0; m < 2; m++)
#pragma unroll
      for (int r = 0; r < 4; r++) {
        int row = wm * 32 + m * 16 + lg * 4 + r;
        atomicAdd(&Alds[row * 2 + 0], pA[m][r][0]);
        atomicAdd(&Alds[row * 2 + 1], pA[m][r][1]);
      }
  }
  __syncthreads();
  if (tid < 128) {
    int row = tid >> 1, c = tid & 1;
    if (m0 + row < M_ROWS) Ag[(size_t)(m0 + row) * 2 + c] = Alds[tid] + b3[c];
  }
}

// ---------- top-k helpers: jax tie semantics (value desc/asc, index asc) ----------
template <bool MIN>
static __device__ __forceinline__ bool better(float v1, int i1, float v2, int i2) {
  if (MIN) return (v1 < v2) || (v1 == v2 && i1 < i2);
  else     return (v1 > v2) || (v1 == v2 && i1 < i2);
}

template <bool MIN>
static __device__ __forceinline__ void merge_lists(float* vL, int* iL, int t, int s) {
  float av[8], ov[8], mv[8];
  int ai[8], oi[8], mi[8];
#pragma unroll
  for (int p = 0; p < 8; p++) {
    av[p] = vL[t * 8 + p];       ai[p] = iL[t * 8 + p];
    ov[p] = vL[(t + s) * 8 + p]; oi[p] = iL[(t + s) * 8 + p];
  }
#pragma unroll
  for (int p = 0; p < 8; p++) {   // top-8 of union = elementwise best(a[p], o[7-p])
    bool b = better<MIN>(av[p], ai[p], ov[7 - p], oi[7 - p]);
    mv[p] = b ? av[p] : ov[7 - p];
    mi[p] = b ? ai[p] : oi[7 - p];
  }
#define CE(i, j)                                                             \
  { if (!better<MIN>(mv[i], mi[i], mv[j], mi[j])) {                          \
      float tv = mv[i]; mv[i] = mv[j]; mv[j] = tv;                           \
      int tii = mi[i]; mi[i] = mi[j]; mi[j] = tii; } }
  CE(0, 4) CE(1, 5) CE(2, 6) CE(3, 7)
  CE(0, 2) CE(1, 3) CE(4, 6) CE(5, 7)
  CE(0, 1) CE(2, 3) CE(4, 5) CE(6, 7)
#undef CE
#pragma unroll
  for (int p = 0; p < 8; p++) { vL[t * 8 + p] = mv[p]; iL[t * 8 + p] = mi[p]; }
}

// ---------- top-k phase 1: 256 blocks, each produces exact sorted top-8/bot-8 of its rows ----
__launch_bounds__(256)
__global__ void topk_p1(const float* __restrict__ Ag, const int* __restrict__ bag_label,
                        float* __restrict__ tkv, int* __restrict__ tki,
                        float* __restrict__ bkv, int* __restrict__ bki) {
  __shared__ float tvL[256 * 8]; __shared__ int tiL[256 * 8];
  __shared__ float bvL[256 * 8]; __shared__ int biL[256 * 8];
  const int t = threadIdx.x;
  const int lab = bag_label[0];
  float tv[8], bv[8]; int ti[8], bi[8];
#pragma unroll
  for (int p = 0; p < 8; p++) {
    tv[p] = -3.4e38f; ti[p] = 0x7fffffff;
    bv[p] =  3.4e38f; bi[p] = 0x7fffffff;
  }
  for (int r = blockIdx.x * 256 + t; r < M_ROWS; r += 65536) {
    float v = Ag[(size_t)r * 2 + lab];
    {
      float cv = v; int ci = r;
#pragma unroll
      for (int p = 0; p < 8; p++) {
        bool b = (cv > tv[p]) || (cv == tv[p] && ci < ti[p]);
        if (b) { float t0 = tv[p]; int t1 = ti[p]; tv[p] = cv; ti[p] = ci; cv = t0; ci = t1; }
      }
    }
    {
      float cv = v; int ci = r;
#pragma unroll
      for (int p = 0; p < 8; p++) {
        bool b = (cv < bv[p]) || (cv == bv[p] && ci < bi[p]);
        if (b) { float t0 = bv[p]; int t1 = bi[p]; bv[p] = cv; bi[p] = ci; cv = t0; ci = t1; }
      }
    }
  }
#pragma unroll
  for (int p = 0; p < 8; p++) {
    tvL[t * 8 + p] = tv[p]; tiL[t * 8 + p] = ti[p];
    bvL[t * 8 + p] = bv[p]; biL[t * 8 + p] = bi[p];
  }
  __syncthreads();
  for (int s = 128; s > 0; s >>= 1) {
    if (t < s) {
      merge_lists<false>(tvL, tiL, t, s);
      merge_lists<true>(bvL, biL, t, s);
    }
    __syncthreads();
  }
  if (t < 8) {
    tkv[blockIdx.x * 8 + t] = tvL[t]; tki[blockIdx.x * 8 + t] = tiL[t];
    bkv[blockIdx.x * 8 + t] = bvL[t]; bki[blockIdx.x * 8 + t] = biL[t];
  }
}

// ---------- top-k phase 2: merge 256 sorted lists ----------
__launch_bounds__(256)
__global__ void topk_p2(const float* __restrict__ tkv, const int* __restrict__ tki,
                        const float* __restrict__ bkv, const int* __restrict__ bki,
                        int* __restrict__ idxout, float* __restrict__ out) {
  __shared__ float tvL[256 * 8]; __shared__ int tiL[256 * 8];
  __shared__ float bvL[256 * 8]; __shared__ int biL[256 * 8];
  const int t = threadIdx.x;
#pragma unroll
  for (int p = 0; p < 8; p++) {
    tvL[t * 8 + p] = tkv[t * 8 + p]; tiL[t * 8 + p] = tki[t * 8 + p];
    bvL[t * 8 + p] = bkv[t * 8 + p]; biL[t * 8 + p] = bki[t * 8 + p];
  }
  __syncthreads();
  for (int s = 128; s > 0; s >>= 1) {
    if (t < s) {
      merge_lists<false>(tvL, tiL, t, s);
      merge_lists<true>(bvL, biL, t, s);
    }
    __syncthreads();
  }
  if (t == 0) {
#pragma unroll
    for (int p = 0; p < 8; p++) {
      idxout[p] = tiL[p];
      idxout[8 + p] = biL[p];
      out[37 + p] = 1.0f;   // ins_labels: ones then zeros
      out[45 + p] = 0.0f;
    }
  }
}

// ---------- kernel H: h=relu(x@Wc+bc); agg partial += A[r]^T h[r]; scatter selected rows ----------
__launch_bounds__(512)
__global__ void kernelH(const float* __restrict__ x,
                        const unsigned short* __restrict__ Wct,
                        const float* __restrict__ bc,
                        const float* __restrict__ Ag,
                        const int* __restrict__ idx,
                        float* __restrict__ aggP,
                        float* __restrict__ hsel) {
  __shared__ unsigned short xl[64 * 32];    // 4KB
  __shared__ unsigned short wl[512 * 32];   // 32KB [col][k]
  __shared__ float aggL[1024];
  __shared__ int selr[16];

  const int tid = threadIdx.x;
  const int lane = tid & 63, wid = tid >> 6;
  const int wm = wid >> 2, wc = wid & 3;
  const int lr = lane & 15, lg = lane >> 4;
  const int m0 = blockIdx.x * 64;

  f32x4 acc[2][8];
#pragma unroll
  for (int m = 0; m < 2; m++)
#pragma unroll
    for (int n = 0; n < 8; n++) acc[m][n] = (f32x4){0.f, 0.f, 0.f, 0.f};

  const int xr = tid >> 3;
  const bool xvalid = (m0 + xr) < M_ROWS;
  const float* xsrc = x + (size_t)(m0 + xr) * 1024 + ((tid & 7) << 2);
  unsigned short* xdst = &xl[tid * 4];

  // W staging via global_load_lds: 4 issues of 4096 shorts (8 waves x 512)
  const unsigned short* wbase = Wct + (size_t)(wid * 16 + (lane >> 2)) * 1024 + ((lane & 3) << 3);
  unsigned short* wdst0 = &wl[wid * 512];
  unsigned short* wdst1 = &wl[4096 + wid * 512];
  unsigned short* wdst2 = &wl[8192 + wid * 512];
  unsigned short* wdst3 = &wl[12288 + wid * 512];

  const bf16x8* ap0 = (const bf16x8*)&xl[(wm * 32 + 0 + lr) * 32 + lg * 8];
  const bf16x8* ap1 = (const bf16x8*)&xl[(wm * 32 + 16 + lr) * 32 + lg * 8];
  const bf16x8* bp[8];
#pragma unroll
  for (int n = 0; n < 8; n++)
    bp[n] = (const bf16x8*)&wl[(wc * 128 + n * 16 + lr) * 32 + lg * 8];

  for (int ks = 0; ks < 32; ks++) {
    const int k0 = ks * 32;
    gload_lds16(wbase + k0, wdst0);
    gload_lds16(wbase + 131072 + k0, wdst1);
    gload_lds16(wbase + 262144 + k0, wdst2);
    gload_lds16(wbase + 393216 + k0, wdst3);
    float4 xv = make_float4(0.f, 0.f, 0.f, 0.f);
    if (xvalid) xv = *(const float4*)(xsrc + k0);
    ushort4 xb;
    xb.x = f2bf(xv.x); xb.y = f2bf(xv.y); xb.z = f2bf(xv.z); xb.w = f2bf(xv.w);
    *(ushort4*)xdst = xb;
    __syncthreads();
    bf16x8 a0 = *ap0, a1 = *ap1;
#pragma unroll
    for (int n = 0; n < 8; n++) {
      bf16x8 bb = *bp[n];
      acc[0][n] = mfma16(a0, bb, acc[0][n]);
      acc[1][n] = mfma16(a1, bb, acc[1][n]);
    }
    __syncthreads();
  }

  // epilogue
  if (tid < 16) {
    int r = idx[tid];
    selr[tid] = (r >= m0 && r < m0 + 64) ? (r - m0) : -1;
  }
  aggL[tid] = 0.0f;
  aggL[tid + 512] = 0.0f;
  __syncthreads();

  float av[2][4][2];
#pragma unroll
  for (int m = 0; m < 2; m++)
#pragma unroll
    for (int r = 0; r < 4; r++) {
      int row = m0 + wm * 32 + m * 16 + lg * 4 + r;
      bool valid = row < M_ROWS;
      av[m][r][0] = valid ? Ag[(size_t)row * 2 + 0] : 0.f;
      av[m][r][1] = valid ? Ag[(size_t)row * 2 + 1] : 0.f;
    }

  float contrib[8][2];
#pragma unroll
  for (int n = 0; n < 8; n++) { contrib[n][0] = 0.f; contrib[n][1] = 0.f; }

#pragma unroll
  for (int n = 0; n < 8; n++) {
    const float bcv = bc[wc * 128 + n * 16 + lr];
#pragma unroll
    for (int m = 0; m < 2; m++)
#pragma unroll
      for (int r = 0; r < 4; r++) {
        float h = fmaxf(acc[m][n][r] + bcv, 0.0f);
        acc[m][n][r] = h;  // keep for hsel scatter
        contrib[n][0] += av[m][r][0] * h;
        contrib[n][1] += av[m][r][1] * h;
      }
  }
#pragma unroll
  for (int n = 0; n < 8; n++)
#pragma unroll
    for (int c = 0; c < 2; c++) {
      contrib[n][c] += __shfl_xor(contrib[n][c], 16, 64);
      contrib[n][c] += __shfl_xor(contrib[n][c], 32, 64);
    }
  if (lg == 0) {
#pragma unroll
    for (int n = 0; n < 8; n++) {
      atomicAdd(&aggL[wc * 128 + n * 16 + lr], contrib[n][0]);
      atomicAdd(&aggL[512 + wc * 128 + n * 16 + lr], contrib[n][1]);
    }
  }
  // scatter selected h rows
#pragma unroll
  for (int s = 0; s < 16; s++) {
    int rl = selr[s];
    if (rl < 0 || (rl >> 5) != wm) continue;
#pragma unroll
    for (int m = 0; m < 2; m++)
#pragma unroll
      for (int r = 0; r < 4; r++)
        if (rl == wm * 32 + m * 16 + lg * 4 + r) {
#pragma unroll
          for (int n = 0; n < 8; n++)
            hsel[s * 512 + wc * 128 + n * 16 + lr] = acc[m][n][r];
        }
  }
  __syncthreads();
  aggP[(size_t)blockIdx.x * 1024 + tid] = aggL[tid];
  aggP[(size_t)blockIdx.x * 1024 + 512 + tid] = aggL[tid + 512];
}

// ---------- reduce agg partials ----------
__launch_bounds__(256)
__global__ void reduce_kernel(const float* __restrict__ aggP, float* __restrict__ agg1) {
  int tcol = (blockIdx.x & 3) * 256 + threadIdx.x;
  int g = blockIdx.x >> 2;
  int b0 = g * 98, b1 = min(NBLK, b0 + 98);
  float s = 0.f;
  for (int b = b0; b < b1; b++) s += aggP[(size_t)b * 1024 + tcol];
  atomicAdd(&agg1[tcol], s);
}

// ---------- slide score / softmax / argmax ----------
__launch_bounds__(1024)
__global__ void score_kernel(const float* __restrict__ agg1, const float* __restrict__ Wbag,
                             const float* __restrict__ bbag, float* __restrict__ out) {
  __shared__ float red[1024];
  int t = threadIdx.x;
  red[t] = agg1[t] * Wbag[t & 511];
  __syncthreads();
  for (int off = 256; off > 0; off >>= 1) {
    if ((t & 511) < off) red[t] += red[t + off];
    __syncthreads();
  }
  if (t == 0) {
    float s0 = red[0] + bbag[0];
    float s1 = red[512] + bbag[0];
    out[0] = s0; out[1] = s1;
    out[2] = (s1 > s0) ? 1.0f : 0.0f;      // argmax, first-max-wins tie
    float mx = fmaxf(s0, s1);
    float e0 = __expf(s0 - mx), e1 = __expf(s1 - mx);
    out[3] = e0 / (e0 + e1);
    out[4] = e1 / (e0 + e1);
  }
}

// ---------- instance head: softmax(hsel @ Wins + bins) ----------
__launch_bounds__(512)
__global__ void ins_kernel(const float* __restrict__ hsel, const float* __restrict__ Wins,
                           const float* __restrict__ bins, float* __restrict__ out) {
  int lane = threadIdx.x & 63;
  int w = threadIdx.x >> 6;  // 8 waves, 2 rows each
#pragma unroll
  for (int si = 0; si < 2; si++) {
    int s = w * 2 + si;
    float z0 = 0.f, z1 = 0.f;
#pragma unroll
    for (int q = 0; q < 8; q++) {
      int c = lane * 8 + q;
      float h = hsel[s * 512 + c];
      z0 += h * Wins[c * 2 + 0];
      z1 += h * Wins[c * 2 + 1];
    }
#pragma unroll
    for (int off = 1; off < 64; off <<= 1) {
      z0 += __shfl_xor(z0, off, 64);
      z1 += __shfl_xor(z1, off, 64);
    }
    if (lane == 0) {
      z0 += bins[0]; z1 += bins[1];
      float mx = fmaxf(z0, z1);
      float e0 = __expf(z0 - mx), e1 = __expf(z1 - mx);
      float d = e0 + e1;
      out[5 + s * 2 + 0] = e0 / d;
      out[5 + s * 2 + 1] = e1 / d;
    }
  }
}

extern "C" void kernel_launch(void* const* d_in, const int* in_sizes, int n_in,
                              void* d_out, int out_size, void* d_ws, size_t ws_size,
                              hipStream_t stream) {
  (void)in_sizes; (void)n_in; (void)out_size; (void)ws_size;
  const float* x    = (const float*)d_in[0];
  const float* Wc   = (const float*)d_in[1];
  const float* bc   = (const float*)d_in[2];
  const float* W1   = (const float*)d_in[3];
  const float* b1   = (const float*)d_in[4];
  const float* W2   = (const float*)d_in[5];
  const float* b2   = (const float*)d_in[6];
  const float* W3   = (const float*)d_in[7];
  const float* b3   = (const float*)d_in[8];
  const float* Wbag = (const float*)d_in[9];
  const float* bbag = (const float*)d_in[10];
  const float* Wins = (const float*)d_in[11];
  const float* bins = (const float*)d_in[12];
  const int* bag_label = (const int*)d_in[13];
  float* out = (float*)d_out;
  char* ws = (char*)d_ws;

  // ws layout (bytes)
  unsigned short* Wct = (unsigned short*)(ws);                    // 1048576
  unsigned short* W1t = (unsigned short*)(ws + 1048576);          // 524288
  unsigned short* W2t = (unsigned short*)(ws + 1572864);          // 524288
  float* Ag   = (float*)(ws + 2097152);                           // 100000*2*4 = 800000
  float* aggP = (float*)(ws + 2897152);                           // 1563*1024*4 = 6402048
  int*   idx  = (int*)  (ws + 9299200);                           // 64
  float* hsel = (float*)(ws + 9299264);                           // 16*512*4 = 32768
  float* agg1 = (float*)(ws + 9332032);                           // 4096
  float* tkv  = (float*)(ws + 9336128);                           // 256*8*4 = 8192
  int*   tki  = (int*)  (ws + 9344320);                           // 8192
  float* bkv  = (float*)(ws + 9352512);                           // 8192
  int*   bki  = (int*)  (ws + 9360704);                           // 8192

  prep_kernel<<<4096, 256, 0, stream>>>(Wc, W1, W2, Wct, W1t, W2t, agg1);
  kernelA<<<NBLK, 512, 0, stream>>>(x, W1t, W2t, b1, b2, W3, b3, Ag);
  topk_p1<<<256, 256, 0, stream>>>(Ag, bag_label, tkv, tki, bkv, bki);
  topk_p2<<<1, 256, 0, stream>>>(tkv, tki, bkv, bki, idx, out);
  kernelH<<<NBLK, 512, 0, stream>>>(x, Wct, bc, Ag, idx, aggP, hsel);
  reduce_kernel<<<64, 256, 0, stream>>>(aggP, agg1);
  score_kernel<<<1, 1024, 0, stream>>>(agg1, Wbag, bbag, out);
  ins_kernel<<<1, 512, 0, stream>>>(hsel, Wins, bins, out);
}